// Round 1
// baseline (495.729 us; speedup 1.0000x reference)
//
#include <hip/hip_runtime.h>
#include <math.h>

#define HH 1024
#define NN 128
#define MM 512

// ---- output layout (floats) ----
// out:0..1023, rw:1024..1151, ww:1152..1279, h:1280..2303, c:2304..3327, new_mem:3328..68863
#define OFF_RW 1024
#define OFF_WW 1152
#define OFF_H  1280
#define OFF_C  2304
#define OFF_NM 3328

// ---- workspace layout (floats) ----
#define WS_GATES   0      // 4096
#define WS_CO      4096   // 1024
#define WS_MNORM   5120   // 128
#define WS_E       5248   // 65536
#define WS_A       70784  // 512
#define WS_KR      71296  // 512
#define WS_KW      71808  // 512
#define WS_RSLOG   72320  // 128
#define WS_WSLOG   72448  // 128
#define WS_FCPART  72576  // 1024
#define WS_SCAL    73600  // 6 (rbeta, rg, rgamma, wbeta, wg, wgamma raw)
#define WS_RWV     73608  // 128
#define WS_WWV     73736  // 128
#define WS_ERASE   73864  // 512
#define WS_READ    74376  // 512

__device__ __forceinline__ float sigmoidf_(float z) { return 1.f / (1.f + expf(-z)); }
__device__ __forceinline__ float softplusf_(float z) {
    return fmaxf(z, 0.f) + log1pf(expf(-fabsf(z)));
}
__device__ __forceinline__ float wave_reduce(float v) {
    #pragma unroll
    for (int off = 32; off > 0; off >>= 1) v += __shfl_down(v, off, 64);
    return v;
}

// K1: LSTM gates GEMV (4096 rows x 1024, two weight mats) + memory row norms
__global__ __launch_bounds__(256) void k1_gates_norms(
    const float* __restrict__ x, const float* __restrict__ h0,
    const float* __restrict__ W_ih, const float* __restrict__ W_hh,
    const float* __restrict__ b_ih, const float* __restrict__ b_hh,
    const float* __restrict__ memory, float* __restrict__ gates,
    float* __restrict__ mem_norm)
{
    int t = threadIdx.x, lane = t & 63, wv = t >> 6;
    if (blockIdx.x < 1024) {
        int r = blockIdx.x * 4 + wv;  // 0..4095
        const float4* wi = (const float4*)(W_ih + (long long)r * HH);
        const float4* wh = (const float4*)(W_hh + (long long)r * HH);
        const float4* x4 = (const float4*)x;
        const float4* h4 = (const float4*)h0;
        float acc = 0.f;
        #pragma unroll
        for (int q = 0; q < 4; ++q) {
            float4 aa = wi[q * 64 + lane], bb = x4[q * 64 + lane];
            acc += aa.x * bb.x + aa.y * bb.y + aa.z * bb.z + aa.w * bb.w;
        }
        #pragma unroll
        for (int q = 0; q < 4; ++q) {
            float4 aa = wh[q * 64 + lane], bb = h4[q * 64 + lane];
            acc += aa.x * bb.x + aa.y * bb.y + aa.z * bb.z + aa.w * bb.w;
        }
        acc = wave_reduce(acc);
        if (lane == 0) gates[r] = acc + b_ih[r] + b_hh[r];
    } else {
        int n = (blockIdx.x - 1024) * 4 + wv;  // 0..127
        const float4* r4 = (const float4*)(memory + n * MM);
        float acc = 0.f;
        #pragma unroll
        for (int q = 0; q < 2; ++q) {
            float4 aa = r4[q * 64 + lane];
            acc += aa.x * aa.x + aa.y * aa.y + aa.z * aa.z + aa.w * aa.w;
        }
        acc = wave_reduce(acc);
        if (lane == 0) mem_norm[n] = sqrtf(acc);
    }
}

// K2: LSTM nonlinearity -> h, c (to out) and co (to ws)
__global__ __launch_bounds__(256) void k2_lstm(
    const float* __restrict__ gates, const float* __restrict__ c0,
    float* __restrict__ out, float* __restrict__ co)
{
    int j = blockIdx.x * 256 + threadIdx.x;  // 0..1023
    float gi = gates[j], gf = gates[j + 1024], gg = gates[j + 2048], go = gates[j + 3072];
    float cn = sigmoidf_(gf) * c0[j] + sigmoidf_(gi) * tanhf(gg);
    float hn = sigmoidf_(go) * tanhf(cn);
    out[OFF_H + j] = hn;
    out[OFF_C + j] = cn;
    co[j] = hn;
}

// K3: all co-dependent GEMVs. Virtual row space:
// [0,65536) e  [65536,66048) a  [66048,66560) kr  [66560,67072) kw
// [67072,67200) rs_logit  [67200,67328) ws_logit  [67328,68352) fc_part
// [68352,68358) scalars
#define K3_ROWS 68358
__global__ __launch_bounds__(256) void k3_gemvs(
    const float* __restrict__ co,
    const float* __restrict__ we_w, const float* __restrict__ we_b,
    const float* __restrict__ wa_w, const float* __restrict__ wa_b,
    const float* __restrict__ rk_w, const float* __restrict__ rk_b,
    const float* __restrict__ wk_w, const float* __restrict__ wk_b,
    const float* __restrict__ rs_w, const float* __restrict__ rs_b,
    const float* __restrict__ sw_w, const float* __restrict__ sw_b,
    const float* __restrict__ fc_w, const float* __restrict__ fc_b,
    const float* __restrict__ rbeta_w, const float* __restrict__ rbeta_b,
    const float* __restrict__ rg_w, const float* __restrict__ rg_b,
    const float* __restrict__ rgamma_w, const float* __restrict__ rgamma_b,
    const float* __restrict__ wbeta_w, const float* __restrict__ wbeta_b,
    const float* __restrict__ wg_w, const float* __restrict__ wg_b,
    const float* __restrict__ wgamma_w, const float* __restrict__ wgamma_b,
    float* __restrict__ e, float* __restrict__ a,
    float* __restrict__ kr, float* __restrict__ kw,
    float* __restrict__ rs_logit, float* __restrict__ ws_logit,
    float* __restrict__ fc_part, float* __restrict__ scal)
{
    int t = threadIdx.x, lane = t & 63, wv = t >> 6;
    long long r = (long long)blockIdx.x * 4 + wv;
    if (r >= K3_ROWS) return;
    const float* row;
    float bias = 0.f;
    float* dst;
    bool sig = false;
    if (r < 65536) {
        row = we_w + r * HH; if (lane == 0) bias = we_b[r]; dst = e + r; sig = true;
    } else if (r < 66048) {
        int i = (int)(r - 65536); row = wa_w + (long long)i * HH; if (lane == 0) bias = wa_b[i]; dst = a + i;
    } else if (r < 66560) {
        int i = (int)(r - 66048); row = rk_w + (long long)i * HH; if (lane == 0) bias = rk_b[i]; dst = kr + i;
    } else if (r < 67072) {
        int i = (int)(r - 66560); row = wk_w + (long long)i * HH; if (lane == 0) bias = wk_b[i]; dst = kw + i;
    } else if (r < 67200) {
        int i = (int)(r - 67072); row = rs_w + (long long)i * HH; if (lane == 0) bias = rs_b[i]; dst = rs_logit + i;
    } else if (r < 67328) {
        int i = (int)(r - 67200); row = sw_w + (long long)i * HH; if (lane == 0) bias = sw_b[i]; dst = ws_logit + i;
    } else if (r < 68352) {
        int i = (int)(r - 67328); row = fc_w + (long long)i * 1536; if (lane == 0) bias = fc_b[i]; dst = fc_part + i;
    } else {
        int i = (int)(r - 68352);
        const float* wsrc; const float* bsrc;
        switch (i) {
            case 0: wsrc = rbeta_w;  bsrc = rbeta_b;  break;
            case 1: wsrc = rg_w;     bsrc = rg_b;     break;
            case 2: wsrc = rgamma_w; bsrc = rgamma_b; break;
            case 3: wsrc = wbeta_w;  bsrc = wbeta_b;  break;
            case 4: wsrc = wg_w;     bsrc = wg_b;     break;
            default: wsrc = wgamma_w; bsrc = wgamma_b; break;
        }
        row = wsrc; if (lane == 0) bias = bsrc[0]; dst = scal + i;
    }
    const float4* r4 = (const float4*)row;
    const float4* c4 = (const float4*)co;
    float acc = 0.f;
    #pragma unroll
    for (int q = 0; q < 4; ++q) {
        float4 aa = r4[q * 64 + lane], bb = c4[q * 64 + lane];
        acc += aa.x * bb.x + aa.y * bb.y + aa.z * bb.z + aa.w * bb.w;
    }
    acc = wave_reduce(acc);
    if (lane == 0) {
        float vv = acc + bias;
        if (sig) vv = sigmoidf_(vv);
        *dst = vv;
    }
}

// K4: addressing for both heads (block 0 = read, block 1 = write). 256 threads.
__global__ __launch_bounds__(256) void k4_address(
    const float* __restrict__ kr, const float* __restrict__ kw,
    const float* __restrict__ scal,
    const float* __restrict__ rs_logit, const float* __restrict__ ws_logit,
    const float* __restrict__ prev_w, const float* __restrict__ mem_norm,
    const float* __restrict__ memory,
    float* __restrict__ out, float* __restrict__ rwv, float* __restrict__ wwv)
{
    int head = blockIdx.x;
    int t = threadIdx.x, lane = t & 63, wv = t >> 6;
    const float* k = head ? kw : kr;
    const float* slog = head ? ws_logit : rs_logit;
    float beta  = softplusf_(scal[head ? 3 : 0]);
    float gg    = sigmoidf_(scal[head ? 4 : 1]);
    float gamma = 1.f + softplusf_(scal[head ? 5 : 2]);

    __shared__ float tmp[256];
    __shared__ float s_cos[128];
    __shared__ float s_s[128];
    __shared__ float s_wg[128];

    // ||k||
    float a0 = k[t], a1 = k[t + 256];
    tmp[t] = a0 * a0 + a1 * a1;
    __syncthreads();
    for (int off = 128; off > 0; off >>= 1) { if (t < off) tmp[t] += tmp[t + off]; __syncthreads(); }
    float k_norm = tmp[0];
    __syncthreads();
    k_norm = sqrtf(k_norm);

    // cos rows: wave wv handles 32 rows
    for (int i = 0; i < 32; ++i) {
        int n = wv * 32 + i;
        const float4* r4 = (const float4*)(memory + n * MM);
        const float4* k4 = (const float4*)k;
        float acc = 0.f;
        #pragma unroll
        for (int q = 0; q < 2; ++q) {
            float4 aa = r4[q * 64 + lane], bb = k4[q * 64 + lane];
            acc += aa.x * bb.x + aa.y * bb.y + aa.z * bb.z + aa.w * bb.w;
        }
        acc = wave_reduce(acc);
        if (lane == 0)
            s_cos[n] = acc / (fmaxf(mem_norm[n], 1e-8f) * fmaxf(k_norm, 1e-8f));
    }
    __syncthreads();

    // w_c = softmax(beta*cos); w_g = g*w_c + (1-g)*prev_read_w
    float z = (t < 128) ? beta * s_cos[t] : -1e30f;
    tmp[t] = z; __syncthreads();
    for (int off = 128; off > 0; off >>= 1) { if (t < off) tmp[t] = fmaxf(tmp[t], tmp[t + off]); __syncthreads(); }
    float zmax = tmp[0]; __syncthreads();
    float ez = (t < 128) ? expf(z - zmax) : 0.f;
    tmp[t] = ez; __syncthreads();
    for (int off = 128; off > 0; off >>= 1) { if (t < off) tmp[t] += tmp[t + off]; __syncthreads(); }
    float zsum = tmp[0]; __syncthreads();
    if (t < 128) s_wg[t] = gg * (ez / zsum) + (1.f - gg) * prev_w[t];

    // s = softmax(s_logit)
    float sl = (t < 128) ? slog[t] : -1e30f;
    tmp[t] = sl; __syncthreads();
    for (int off = 128; off > 0; off >>= 1) { if (t < off) tmp[t] = fmaxf(tmp[t], tmp[t + off]); __syncthreads(); }
    float smax = tmp[0]; __syncthreads();
    float es = (t < 128) ? expf(sl - smax) : 0.f;
    tmp[t] = es; __syncthreads();
    for (int off = 128; off > 0; off >>= 1) { if (t < off) tmp[t] += tmp[t + off]; __syncthreads(); }
    float ssum = tmp[0]; __syncthreads();
    if (t < 128) s_s[t] = es / ssum;
    __syncthreads();

    // circular conv + sharpen
    float wt = 0.f;
    if (t < 128) {
        #pragma unroll 8
        for (int j = 0; j < 128; ++j) wt += s_wg[j] * s_s[(t - j) & 127];
        wt = powf(wt, gamma);
    }
    tmp[t] = (t < 128) ? wt : 0.f;
    __syncthreads();
    for (int off = 128; off > 0; off >>= 1) { if (t < off) tmp[t] += tmp[t + off]; __syncthreads(); }
    float wsum = tmp[0]; __syncthreads();
    if (t < 128) {
        float wf = wt / (wsum + 1e-16f);
        out[(head ? OFF_WW : OFF_RW) + t] = wf;
        (head ? wwv : rwv)[t] = wf;
    }
}

// K5a: erase[m] = sum_n ww[n]*e[n,m]; read[m] = sum_n rw[n]*mem[n,m]
__global__ __launch_bounds__(256) void k5a_contract(
    const float* __restrict__ e, const float* __restrict__ memory,
    const float* __restrict__ wwv, const float* __restrict__ rwv,
    float* __restrict__ erase, float* __restrict__ readv)
{
    int b = blockIdx.x, t = threadIdx.x;
    if (b < 2) {
        int m = b * 256 + t;
        float acc = 0.f;
        for (int n = 0; n < 128; ++n) acc += wwv[n] * e[n * MM + m];
        erase[m] = acc;
    } else {
        int m = (b - 2) * 256 + t;
        float acc = 0.f;
        for (int n = 0; n < 128; ++n) acc += rwv[n] * memory[n * MM + m];
        readv[m] = acc;
    }
}

// K5b: new_mem + fc epilogue
__global__ __launch_bounds__(256) void k5b_final(
    const float* __restrict__ memory, const float* __restrict__ erase,
    const float* __restrict__ wwv, const float* __restrict__ a,
    const float* __restrict__ fc_w, const float* __restrict__ fc_part,
    const float* __restrict__ readv, float* __restrict__ out)
{
    int b = blockIdx.x, t = threadIdx.x;
    if (b < 256) {
        int idx = b * 256 + t;
        int n = idx >> 9, m = idx & 511;
        out[OFF_NM + idx] = memory[idx] * (1.f - erase[m]) + wwv[n] * a[m];
    } else {
        int w = (b - 256) * 4 + (t >> 6);  // fc row 0..1023
        int lane = t & 63;
        const float4* r4 = (const float4*)(fc_w + (long long)w * 1536 + 1024);
        const float4* v4 = (const float4*)readv;
        float acc = 0.f;
        #pragma unroll
        for (int q = 0; q < 2; ++q) {
            float4 aa = r4[q * 64 + lane], bb = v4[q * 64 + lane];
            acc += aa.x * bb.x + aa.y * bb.y + aa.z * bb.z + aa.w * bb.w;
        }
        acc = wave_reduce(acc);
        if (lane == 0) out[w] = fc_part[w] + acc;
    }
}

extern "C" void kernel_launch(void* const* d_in, const int* in_sizes, int n_in,
                              void* d_out, int out_size, void* d_ws, size_t ws_size,
                              hipStream_t stream)
{
    const float* x           = (const float*)d_in[0];
    const float* prev_read_w = (const float*)d_in[1];
    // d_in[2] (prev_write_w) is unused — reference passes prev_read_w to both heads
    const float* h0      = (const float*)d_in[3];
    const float* c0      = (const float*)d_in[4];
    const float* memory  = (const float*)d_in[5];
    const float* W_ih    = (const float*)d_in[6];
    const float* W_hh    = (const float*)d_in[7];
    const float* b_ih    = (const float*)d_in[8];
    const float* b_hh    = (const float*)d_in[9];
    const float* rk_w    = (const float*)d_in[10];
    const float* rk_b    = (const float*)d_in[11];
    const float* rbeta_w = (const float*)d_in[12];
    const float* rbeta_b = (const float*)d_in[13];
    const float* rg_w    = (const float*)d_in[14];
    const float* rg_b    = (const float*)d_in[15];
    const float* rs_w    = (const float*)d_in[16];
    const float* rs_b    = (const float*)d_in[17];
    const float* rgamma_w = (const float*)d_in[18];
    const float* rgamma_b = (const float*)d_in[19];
    const float* wk_w    = (const float*)d_in[20];
    const float* wk_b    = (const float*)d_in[21];
    const float* wbeta_w = (const float*)d_in[22];
    const float* wbeta_b = (const float*)d_in[23];
    const float* wg_w    = (const float*)d_in[24];
    const float* wg_b    = (const float*)d_in[25];
    const float* sw_w    = (const float*)d_in[26];
    const float* sw_b    = (const float*)d_in[27];
    const float* wgamma_w = (const float*)d_in[28];
    const float* wgamma_b = (const float*)d_in[29];
    const float* we_w    = (const float*)d_in[30];
    const float* we_b    = (const float*)d_in[31];
    const float* wa_w    = (const float*)d_in[32];
    const float* wa_b    = (const float*)d_in[33];
    const float* fc_w    = (const float*)d_in[34];
    const float* fc_b    = (const float*)d_in[35];

    float* ws  = (float*)d_ws;
    float* out = (float*)d_out;

    float* gates    = ws + WS_GATES;
    float* co       = ws + WS_CO;
    float* mem_norm = ws + WS_MNORM;
    float* e        = ws + WS_E;
    float* a        = ws + WS_A;
    float* kr       = ws + WS_KR;
    float* kw       = ws + WS_KW;
    float* rs_logit = ws + WS_RSLOG;
    float* ws_logit = ws + WS_WSLOG;
    float* fc_part  = ws + WS_FCPART;
    float* scal     = ws + WS_SCAL;
    float* rwv      = ws + WS_RWV;
    float* wwv      = ws + WS_WWV;
    float* erase    = ws + WS_ERASE;
    float* readv    = ws + WS_READ;

    k1_gates_norms<<<1056, 256, 0, stream>>>(x, h0, W_ih, W_hh, b_ih, b_hh,
                                             memory, gates, mem_norm);
    k2_lstm<<<4, 256, 0, stream>>>(gates, c0, out, co);
    k3_gemvs<<<(K3_ROWS + 3) / 4, 256, 0, stream>>>(
        co, we_w, we_b, wa_w, wa_b, rk_w, rk_b, wk_w, wk_b, rs_w, rs_b,
        sw_w, sw_b, fc_w, fc_b,
        rbeta_w, rbeta_b, rg_w, rg_b, rgamma_w, rgamma_b,
        wbeta_w, wbeta_b, wg_w, wg_b, wgamma_w, wgamma_b,
        e, a, kr, kw, rs_logit, ws_logit, fc_part, scal);
    k4_address<<<2, 256, 0, stream>>>(kr, kw, scal, rs_logit, ws_logit,
                                      prev_read_w, mem_norm, memory,
                                      out, rwv, wwv);
    k5a_contract<<<4, 256, 0, stream>>>(e, memory, wwv, rwv, erase, readv);
    k5b_final<<<512, 256, 0, stream>>>(memory, erase, wwv, a, fc_w, fc_part,
                                       readv, out);
}